// Round 20
// baseline (1060.716 us; speedup 1.0000x reference)
//
#include <hip/hip_runtime.h>
#include <hip/hip_bf16.h>

#define NN 50000
#define NE 1000000
#define NF 32
#define ED 16
#define HD 64
#define BN_EPS 1e-5f

typedef unsigned short u16;
typedef __attribute__((ext_vector_type(8))) short bf16x8;
typedef __attribute__((ext_vector_type(4))) float f32x4;

// wave-level LDS fence: ds ops complete + no compiler reordering (rule #18)
#define WAVE_SYNC() do { \
    asm volatile("s_waitcnt lgkmcnt(0)" ::: "memory"); \
    __builtin_amdgcn_sched_barrier(0); \
} while (0)

__device__ __forceinline__ u16 f2b(float x)
{
    __hip_bfloat16 b = __float2bfloat16(x);
    u16 u; __builtin_memcpy(&u, &b, 2); return u;
}
__device__ __forceinline__ float b2f(u16 u)
{
    uint v = (uint)u << 16; float f; __builtin_memcpy(&f, &v, 4); return f;
}

// ---------------- diag: fill an f32 region with a sentinel constant
__global__ __launch_bounds__(256) void k_fill(float* p, float v, size_t n)
{
    size_t i = (size_t)blockIdx.x * 256 + threadIdx.x;
    if (i < n) p[i] = v;
}

// rank-4 update: o += t * W[0:4][:]  (weights wave-uniform)
__device__ __forceinline__ void gemm4(float (&o)[HD], float4 t, const float* __restrict__ Wr)
{
    #pragma unroll
    for (int f = 0; f < HD; f++) o[f] = fmaf(t.x, Wr[f], o[f]);
    #pragma unroll
    for (int f = 0; f < HD; f++) o[f] = fmaf(t.y, Wr[HD + f], o[f]);
    #pragma unroll
    for (int f = 0; f < HD; f++) o[f] = fmaf(t.z, Wr[2 * HD + f], o[f]);
    #pragma unroll
    for (int f = 0; f < HD; f++) o[f] = fmaf(t.w, Wr[3 * HD + f], o[f]);
}

// pack 8 consecutive f32 -> bf16x8 fragment (in registers)
__device__ __forceinline__ bf16x8 pack8(const float* __restrict__ p)
{
    float4 v0 = ((const float4*)p)[0];
    float4 v1 = ((const float4*)p)[1];
    union { uint u[4]; bf16x8 v; } r;
    r.u[0] = (uint)f2b(v0.x) | ((uint)f2b(v0.y) << 16);
    r.u[1] = (uint)f2b(v0.z) | ((uint)f2b(v0.w) << 16);
    r.u[2] = (uint)f2b(v1.x) | ((uint)f2b(v1.y) << 16);
    r.u[3] = (uint)f2b(v1.z) | ((uint)f2b(v1.w) << 16);
    return r.v;
}

// ---------------- prep: W1[l][k][f] (f32) -> w1t[l][f][k] (bf16), k=0..191
__global__ __launch_bounds__(256) void k_prep_w1(const float* __restrict__ W, u16* __restrict__ out)
{
    int idx = blockIdx.x * 256 + threadIdx.x;
    if (idx >= 2 * 192 * HD) return;
    int l = idx / (192 * HD), r = idx % (192 * HD), k = r / HD, f = r % HD;
    out[l * 192 * HD + f * 192 + k] = f2b(W[idx]);
}
// ---------------- prep: 2 layers of [64][64] (k,f) -> (f,k) bf16
__global__ __launch_bounds__(256) void k_prep_w64(const float* __restrict__ W, u16* __restrict__ out)
{
    int idx = blockIdx.x * 256 + threadIdx.x;
    if (idx >= 2 * HD * HD) return;
    int l = idx / (HD * HD), r = idx % (HD * HD), k = r / HD, f = r % HD;
    out[l * HD * HD + f * HD + k] = f2b(W[idx]);
}
// ---------------- prep: edge_W [16][64] (k,f) -> padded [64][32] (f,k), k>=16 -> 0
__global__ __launch_bounds__(256) void k_prep_wpad(const float* __restrict__ W, u16* __restrict__ out)
{
    int idx = blockIdx.x * 256 + threadIdx.x;
    if (idx >= HD * 32) return;
    int f = idx / 32, k = idx % 32;
    out[f * 32 + k] = (k < ED) ? f2b(W[k * HD + f]) : (u16)0;
}

// ---------------- K1: h = x @ node_W + node_b  (wave per node, K=32 via shfl)
__global__ __launch_bounds__(256) void k_node_proj(
    const float* __restrict__ x, const float* __restrict__ W,
    const float* __restrict__ b, float* __restrict__ h)
{
    __shared__ float sW[NF * HD];   // 8 KB
    for (int t = threadIdx.x; t < NF * HD; t += 256) sW[t] = W[t];
    __syncthreads();
    int lane = threadIdx.x & 63, wv = threadIdx.x >> 6;
    int n = blockIdx.x * 4 + wv;
    if (n >= NN) return;
    float a = (lane < NF) ? x[(size_t)n * NF + lane] : 0.f;
    float acc = b[lane];
    #pragma unroll
    for (int k = 0; k < NF; k++) acc = fmaf(__shfl(a, k), sW[k * HD + lane], acc);
    h[(size_t)n * HD + lane] = acc;
}

// coalesced eab write from LDS: 32 edges x 128B, 4 passes x 64 lanes x 16B
__device__ __forceinline__ void eab_write_coalesced(
    u16* __restrict__ eab, const u16* sOw, size_t base, int lane)
{
    #pragma unroll
    for (int p = 0; p < 4; p++) {
        int id = p * 64 + lane;
        int el = id >> 3, q = id & 7;
        *(bf16x8*)&eab[(base + el) * HD + q * 8] =
            *(const bf16x8*)&sOw[el * 72 + q * 8];
    }
}

// ---------------- K2+K3 FUSED: eab = bf16(attr@edge_W+b); msg = relu(h[src]+eab@welt+belin)
__global__ __launch_bounds__(256) void k_edge_proj_gine(
    const float* __restrict__ attr, const float* __restrict__ h,
    const int* __restrict__ src, const int* __restrict__ dst,
    const u16* __restrict__ wpadt, const float* __restrict__ eb,
    const u16* __restrict__ welt, const float* __restrict__ belin,
    u16* __restrict__ eab, float* __restrict__ agg)
{
    __shared__ u16 sO[4][32 * 72];   // 18 KB
    const int lane = threadIdx.x & 63, wv = threadIdx.x >> 6;
    const size_t base = ((size_t)blockIdx.x * 4 + wv) * 32;
    if (base >= NE) return;
    u16* sOw = sO[wv];
    const int c = lane & 15, g = lane >> 4;

    // ---- A-frags from attr: K=16 real (g<2), zero else ----
    bf16x8 zero8 = {0, 0, 0, 0, 0, 0, 0, 0};
    bf16x8 ap[2];
    #pragma unroll
    for (int s = 0; s < 2; s++)
        ap[s] = (g < 2) ? pack8(attr + (base + 16 * s + c) * ED + 8 * g) : zero8;

    // ---- proj MFMA: ea = attr @ edge_W + eb ----
    f32x4 acc[2][4];
    #pragma unroll
    for (int s = 0; s < 2; s++)
        #pragma unroll
        for (int tt = 0; tt < 4; tt++) {
            float bv = eb[tt * 16 + c];
            acc[s][tt] = (f32x4){bv, bv, bv, bv};
        }
    #pragma unroll
    for (int tt = 0; tt < 4; tt++) {
        bf16x8 bw = *(const bf16x8*)&wpadt[(tt * 16 + c) * 32 + 8 * g];
        acc[0][tt] = __builtin_amdgcn_mfma_f32_16x16x32_bf16(ap[0], bw, acc[0][tt], 0, 0, 0);
        acc[1][tt] = __builtin_amdgcn_mfma_f32_16x16x32_bf16(ap[1], bw, acc[1][tt], 0, 0, 0);
    }
    // ---- write ea to LDS (transpose buffer) ----
    #pragma unroll
    for (int s = 0; s < 2; s++)
        #pragma unroll
        for (int tt = 0; tt < 4; tt++)
            #pragma unroll
            for (int r = 0; r < 4; r++)
                sOw[(16 * s + 4 * g + r) * 72 + tt * 16 + c] = f2b(acc[s][tt][r]);
    WAVE_SYNC();
    // ---- coalesced global eab write from LDS ----
    eab_write_coalesced(eab, sOw, base, lane);

    // ---- fused gine_msg(0): msg = relu(h[src] + eab @ welt + belin) ----
    bf16x8 A3[2][2];
    #pragma unroll
    for (int s = 0; s < 2; s++) {
        A3[s][0] = *(const bf16x8*)&sOw[(16 * s + c) * 72 + 8 * g];
        A3[s][1] = *(const bf16x8*)&sOw[(16 * s + c) * 72 + 32 + 8 * g];
    }
    f32x4 acc3[2][4];
    #pragma unroll
    for (int s = 0; s < 2; s++)
        #pragma unroll
        for (int tt = 0; tt < 4; tt++) {
            float bv = belin[tt * 16 + c];
            acc3[s][tt] = (f32x4){bv, bv, bv, bv};
        }
    #pragma unroll
    for (int ki = 0; ki < 2; ki++)
        #pragma unroll
        for (int tt = 0; tt < 4; tt++) {
            bf16x8 bw = *(const bf16x8*)&welt[(tt * 16 + c) * HD + ki * 32 + 8 * g];
            acc3[0][tt] = __builtin_amdgcn_mfma_f32_16x16x32_bf16(A3[0][ki], bw, acc3[0][tt], 0, 0, 0);
            acc3[1][tt] = __builtin_amdgcn_mfma_f32_16x16x32_bf16(A3[1][ki], bw, acc3[1][tt], 0, 0, 0);
        }
    int sv2[2][4], dv2[2][4];
    #pragma unroll
    for (int s = 0; s < 2; s++)
        #pragma unroll
        for (int r = 0; r < 4; r++) {
            sv2[s][r] = src[base + 16 * s + 4 * g + r];
            dv2[s][r] = dst[base + 16 * s + 4 * g + r];
        }
    #pragma unroll
    for (int s = 0; s < 2; s++)
        #pragma unroll
        for (int tt = 0; tt < 4; tt++)
            #pragma unroll
            for (int r = 0; r < 4; r++) {
                float m = fmaxf(acc3[s][tt][r] + h[(size_t)sv2[s][r] * HD + tt * 16 + c], 0.f);
                unsafeAtomicAdd(&agg[(size_t)dv2[s][r] * HD + tt * 16 + c], m);
            }
}

// ---------------- K4: out2 = mlp2(relu(mlp1(h+agg)))  (thread per node)
__global__ __launch_bounds__(256) void k_node_mlp(
    const float* __restrict__ h, const float* __restrict__ agg,
    const float* __restrict__ W1, const float* __restrict__ b1,
    const float* __restrict__ W2, const float* __restrict__ b2,
    float* __restrict__ out2)
{
    int n = blockIdx.x * 256 + threadIdx.x;
    if (n >= NN) return;
    float o[HD];
    #pragma unroll
    for (int f = 0; f < HD; f++) o[f] = b1[f];
    const float4* hr = (const float4*)(h + (size_t)n * HD);
    const float4* ar = (const float4*)(agg + (size_t)n * HD);
    #pragma unroll 4
    for (int k4 = 0; k4 < 16; k4++) {
        float4 t1 = hr[k4], t2 = ar[k4];
        float4 t = make_float4(t1.x + t2.x, t1.y + t2.y, t1.z + t2.z, t1.w + t2.w);
        gemm4(o, t, W1 + (k4 * 4) * HD);
    }
    #pragma unroll
    for (int k = 0; k < HD; k++) o[k] = fmaxf(o[k], 0.f);
    #pragma unroll
    for (int c = 0; c < 4; c++) {
        float p[16];
        #pragma unroll
        for (int j = 0; j < 16; j++) p[j] = b2[c * 16 + j];
        for (int k = 0; k < HD; k++) {
            const float* Wr = W2 + k * HD + c * 16;
            #pragma unroll
            for (int j = 0; j < 16; j++) p[j] = fmaf(o[k], Wr[j], p[j]);
        }
        float4* orow = (float4*)(out2 + (size_t)n * HD + c * 16);
        #pragma unroll
        for (int q = 0; q < 4; q++)
            orow[q] = make_float4(p[4*q], p[4*q+1], p[4*q+2], p[4*q+3]);
    }
}

// ---------------- K4b: BN stats reduction (lane = feature, coalesced rows)
__global__ __launch_bounds__(256) void k_bnstats(
    const float* __restrict__ out2, float* __restrict__ bnst)
{
    int f = threadIdx.x & 63;
    int row0 = blockIdx.x * 4 + (threadIdx.x >> 6);
    float s = 0.f, q = 0.f;
    for (int r = row0; r < NN; r += gridDim.x * 4) {
        float v = out2[(size_t)r * HD + f];
        s += v; q += v * v;
    }
    unsafeAtomicAdd(&bnst[f], s);
    unsafeAtomicAdd(&bnst[HD + f], q);
}

// ---------------- K5: BN + h = (h + relu(out2*sc+sh)) * 0.5 ; also bf16 h copy
__global__ __launch_bounds__(256) void k_bn_h(
    const float* __restrict__ out2, const float* __restrict__ bnst,
    const float* __restrict__ gamma, const float* __restrict__ beta,
    float* __restrict__ h, u16* __restrict__ hbf, float* __restrict__ hout, int last)
{
    size_t idx = (size_t)blockIdx.x * 256 + threadIdx.x;
    if (idx >= (size_t)NN * HD) return;
    int f = (int)(idx & 63);
    float mu  = bnst[f] * (1.f / NN);
    float var = bnst[HD + f] * (1.f / NN) - mu * mu;
    float sc  = gamma[f] * rsqrtf(var + BN_EPS);
    float sh  = beta[f] - mu * sc;
    float o   = fmaxf(fmaf(out2[idx], sc, sh), 0.f);
    float hn  = (h[idx] + o) * 0.5f;
    h[idx] = hn;
    hbf[idx] = f2b(hn);
    if (last) hout[idx] = hn;
}

// shared core: layer-1 + layer-2 MFMA for the edge MLP (32 edges/wave)
__device__ __forceinline__ void edge_mlp_core(
    const u16* __restrict__ hbf, const u16* __restrict__ eab,
    const int* __restrict__ src, const int* __restrict__ dst,
    const u16* __restrict__ w1t, const float* __restrict__ b1,
    const u16* __restrict__ w2t, const float* __restrict__ b2,
    u16* sOw, size_t base, int c, int g, f32x4 (&acc2)[2][4])
{
    int sv[2], dv[2];
    #pragma unroll
    for (int s = 0; s < 2; s++) {
        sv[s] = src[base + 16 * s + c];
        dv[s] = dst[base + 16 * s + c];
    }
    bf16x8 A[3][2][2];
    #pragma unroll
    for (int s = 0; s < 2; s++) {
        const u16* hs = &hbf[(size_t)sv[s] * HD + 8 * g];
        A[0][s][0] = *(const bf16x8*)hs;
        A[0][s][1] = *(const bf16x8*)(hs + 32);
        const u16* hd = &hbf[(size_t)dv[s] * HD + 8 * g];
        A[1][s][0] = *(const bf16x8*)hd;
        A[1][s][1] = *(const bf16x8*)(hd + 32);
        const u16* ep = &eab[(base + 16 * s + c) * HD + 8 * g];
        A[2][s][0] = *(const bf16x8*)ep;
        A[2][s][1] = *(const bf16x8*)(ep + 32);
    }
    f32x4 acc[2][4];
    #pragma unroll
    for (int s = 0; s < 2; s++)
        #pragma unroll
        for (int tt = 0; tt < 4; tt++) {
            float bv = b1[tt * 16 + c];
            acc[s][tt] = (f32x4){bv, bv, bv, bv};
        }
    #pragma unroll
    for (int sec = 0; sec < 3; sec++)
        #pragma unroll
        for (int ki = 0; ki < 2; ki++)
            #pragma unroll
            for (int tt = 0; tt < 4; tt++) {
                bf16x8 bw = *(const bf16x8*)&w1t[(tt * 16 + c) * 192 + sec * 64 + ki * 32 + 8 * g];
                acc[0][tt] = __builtin_amdgcn_mfma_f32_16x16x32_bf16(A[sec][0][ki], bw, acc[0][tt], 0, 0, 0);
                acc[1][tt] = __builtin_amdgcn_mfma_f32_16x16x32_bf16(A[sec][1][ki], bw, acc[1][tt], 0, 0, 0);
            }
    #pragma unroll
    for (int s = 0; s < 2; s++)
        #pragma unroll
        for (int tt = 0; tt < 4; tt++)
            #pragma unroll
            for (int r = 0; r < 4; r++)
                sOw[(16 * s + 4 * g + r) * 72 + tt * 16 + c] = f2b(fmaxf(acc[s][tt][r], 0.f));
    WAVE_SYNC();
    bf16x8 A2[2][2];
    #pragma unroll
    for (int s = 0; s < 2; s++) {
        A2[s][0] = *(const bf16x8*)&sOw[(16 * s + c) * 72 + 8 * g];
        A2[s][1] = *(const bf16x8*)&sOw[(16 * s + c) * 72 + 32 + 8 * g];
    }
    WAVE_SYNC();
    #pragma unroll
    for (int s = 0; s < 2; s++)
        #pragma unroll
        for (int tt = 0; tt < 4; tt++) {
            float bv = b2[tt * 16 + c];
            acc2[s][tt] = (f32x4){bv, bv, bv, bv};
        }
    #pragma unroll
    for (int ki = 0; ki < 2; ki++)
        #pragma unroll
        for (int tt = 0; tt < 4; tt++) {
            bf16x8 bw = *(const bf16x8*)&w2t[(tt * 16 + c) * HD + ki * 32 + 8 * g];
            acc2[0][tt] = __builtin_amdgcn_mfma_f32_16x16x32_bf16(A2[0][ki], bw, acc2[0][tt], 0, 0, 0);
            acc2[1][tt] = __builtin_amdgcn_mfma_f32_16x16x32_bf16(A2[1][ki], bw, acc2[1][tt], 0, 0, 0);
        }
}

// ---------------- K6a: edge_upd layer0 FUSED with gine_msg layer1
__global__ __launch_bounds__(256) void k_edge_upd_fused(
    const u16* __restrict__ hbf, u16* __restrict__ eab,
    const int* __restrict__ src, const int* __restrict__ dst,
    const u16* __restrict__ w1t, const float* __restrict__ b1,
    const u16* __restrict__ w2t, const float* __restrict__ b2,
    const float* __restrict__ h, const u16* __restrict__ welt,
    const float* __restrict__ belin, float* __restrict__ agg)
{
    __shared__ u16 sO[4][32 * 72];   // 18 KB
    const int lane = threadIdx.x & 63, wv = threadIdx.x >> 6;
    const size_t base = ((size_t)blockIdx.x * 4 + wv) * 32;
    if (base >= NE) return;
    u16* sOw = sO[wv];
    const int c = lane & 15, g = lane >> 4;

    f32x4 acc2[2][4];
    edge_mlp_core(hbf, eab, src, dst, w1t, b1, w2t, b2, sOw, base, c, g, acc2);

    // ---- eab_new = bf16(eab + 0.5*upd): LDS first, then coalesced global ----
    #pragma unroll
    for (int s = 0; s < 2; s++)
        #pragma unroll
        for (int tt = 0; tt < 4; tt++)
            #pragma unroll
            for (int r = 0; r < 4; r++) {
                size_t a = (base + 16 * s + 4 * g + r) * HD + tt * 16 + c;
                sOw[(16 * s + 4 * g + r) * 72 + tt * 16 + c] =
                    f2b(b2f(eab[a]) + 0.5f * acc2[s][tt][r]);
            }
    WAVE_SYNC();
    eab_write_coalesced(eab, sOw, base, lane);

    // ---- fused gine_msg (layer 1): msg = relu(h[src] + eab_new @ welt + belin) ----
    bf16x8 A3[2][2];
    #pragma unroll
    for (int s = 0; s < 2; s++) {
        A3[s][0] = *(const bf16x8*)&sOw[(16 * s + c) * 72 + 8 * g];
        A3[s][1] = *(const bf16x8*)&sOw[(16 * s + c) * 72 + 32 + 8 * g];
    }
    f32x4 acc3[2][4];
    #pragma unroll
    for (int s = 0; s < 2; s++)
        #pragma unroll
        for (int tt = 0; tt < 4; tt++) {
            float bv = belin[tt * 16 + c];
            acc3[s][tt] = (f32x4){bv, bv, bv, bv};
        }
    #pragma unroll
    for (int ki = 0; ki < 2; ki++)
        #pragma unroll
        for (int tt = 0; tt < 4; tt++) {
            bf16x8 bw = *(const bf16x8*)&welt[(tt * 16 + c) * HD + ki * 32 + 8 * g];
            acc3[0][tt] = __builtin_amdgcn_mfma_f32_16x16x32_bf16(A3[0][ki], bw, acc3[0][tt], 0, 0, 0);
            acc3[1][tt] = __builtin_amdgcn_mfma_f32_16x16x32_bf16(A3[1][ki], bw, acc3[1][tt], 0, 0, 0);
        }
    int sv2[2][4], dv2[2][4];
    #pragma unroll
    for (int s = 0; s < 2; s++)
        #pragma unroll
        for (int r = 0; r < 4; r++) {
            sv2[s][r] = src[base + 16 * s + 4 * g + r];
            dv2[s][r] = dst[base + 16 * s + 4 * g + r];
        }
    #pragma unroll
    for (int s = 0; s < 2; s++)
        #pragma unroll
        for (int tt = 0; tt < 4; tt++)
            #pragma unroll
            for (int r = 0; r < 4; r++) {
                float m = fmaxf(acc3[s][tt][r] + h[(size_t)sv2[s][r] * HD + tt * 16 + c], 0.f);
                unsafeAtomicAdd(&agg[(size_t)dv2[s][r] * HD + tt * 16 + c], m);
            }
}

// ---------------- K6b: edge_upd layer1 FINAL: f32 output to d_out
__global__ __launch_bounds__(256) void k_edge_upd_final(
    const u16* __restrict__ hbf, const u16* __restrict__ eab,
    float* __restrict__ eaout,
    const int* __restrict__ src, const int* __restrict__ dst,
    const u16* __restrict__ w1t, const float* __restrict__ b1,
    const u16* __restrict__ w2t, const float* __restrict__ b2)
{
    __shared__ u16 sO[4][32 * 72];   // 18 KB
    const int lane = threadIdx.x & 63, wv = threadIdx.x >> 6;
    const size_t base = ((size_t)blockIdx.x * 4 + wv) * 32;
    if (base >= NE) return;
    u16* sOw = sO[wv];
    const int c = lane & 15, g = lane >> 4;

    f32x4 acc2[2][4];
    edge_mlp_core(hbf, eab, src, dst, w1t, b1, w2t, b2, sOw, base, c, g, acc2);

    // f32 writes: lanes c=0..15 cover 64B contiguous per (s,tt,r) — already coalesced
    #pragma unroll
    for (int s = 0; s < 2; s++)
        #pragma unroll
        for (int tt = 0; tt < 4; tt++)
            #pragma unroll
            for (int r = 0; r < 4; r++) {
                size_t a = (base + 16 * s + 4 * g + r) * HD + tt * 16 + c;
                eaout[a] = b2f(eab[a]) + 0.5f * acc2[s][tt][r];
            }
}

extern "C" void kernel_launch(void* const* d_in, const int* in_sizes, int n_in,
                              void* d_out, int out_size, void* d_ws, size_t ws_size,
                              hipStream_t stream)
{
    const float* x        = (const float*)d_in[0];
    const int*   ei       = (const int*)d_in[1];
    const float* eattr    = (const float*)d_in[2];
    const float* node_W   = (const float*)d_in[3];
    const float* node_b   = (const float*)d_in[4];
    const float* edge_W   = (const float*)d_in[5];
    const float* edge_b   = (const float*)d_in[6];
    const float* elin_W   = (const float*)d_in[7];
    const float* elin_b   = (const float*)d_in[8];
    const float* mlp1_W   = (const float*)d_in[9];
    const float* mlp1_b   = (const float*)d_in[10];
    const float* mlp2_W   = (const float*)d_in[11];
    const float* mlp2_b   = (const float*)d_in[12];
    const float* emlp1_W  = (const float*)d_in[13];
    const float* emlp1_b  = (const float*)d_in[14];
    const float* emlp2_W  = (const float*)d_in[15];
    const float* emlp2_b  = (const float*)d_in[16];
    const float* bn_gamma = (const float*)d_in[17];
    const float* bn_beta  = (const float*)d_in[18];

    // OUTPUT IS FLOAT32: h at [0, 3.2M), ea at [3.2M, 67.2M)
    float* hout = (float*)d_out;
    float* eaout = hout + (size_t)NN * HD;

    const int* src = ei;          // edge_index row-major (2, NE)
    const int* dst = ei + NE;

    float* hbuf = (float*)d_ws;
    float* agg  = hbuf + (size_t)NN * HD;
    float* out2 = agg + (size_t)NN * HD;
    float* bnst = out2 + (size_t)NN * HD;
    u16*   w1t  = (u16*)(bnst + 128);          // [2][64][192] bf16
    u16*   w2t  = w1t + 2 * 192 * HD;          // [2][64][64]  bf16
    u16*   welt = w2t + 2 * HD * HD;           // [2][64][64]  bf16 (elin)
    u16*   wpad = welt + 2 * HD * HD;          // [64][32]     bf16 (edge proj, padded)
    u16*   hbf  = wpad + HD * 32;              // [NN][64] bf16
    u16*   eab  = hbf + (size_t)NN * HD;       // [NE][64] bf16 (128 MB)
    size_t base_need = ((size_t)NN * HD * 3 + 128) * sizeof(float)
                     + (2 * 192 * HD + 4 * HD * HD + HD * 32 + (size_t)NN * HD
                        + (size_t)NE * HD) * sizeof(u16);

    // ---- host-side sanity sentinels (decodable through absmax) ----
    static const int exp_sizes[19] = {
        1600000, 2000000, 16000000, 2048, 64, 1024, 64,
        8192, 128, 8192, 128, 8192, 128, 24576, 128, 8192, 128, 128, 128};
    float sentinel = 0.f;
    if (n_in != 19) sentinel = 6000.f;
    else {
        for (int i = 0; i < 19; i++)
            if (in_sizes[i] != exp_sizes[i]) { sentinel = 2000.f + 32.f * i; break; }
    }
    if (sentinel == 0.f && ws_size < base_need) sentinel = 7000.f;
    if (sentinel != 0.f) {
        k_fill<<<dim3((unsigned)(((size_t)NN * HD + 255) / 256)), dim3(256), 0, stream>>>(
            hout, sentinel, (size_t)NN * HD);
        k_fill<<<dim3((unsigned)(((size_t)NE * HD + 255) / 256)), dim3(256), 0, stream>>>(
            eaout, 0.f, (size_t)NE * HD);
        return;
    }

    dim3 b256(256);
    const unsigned WG2 = (NE + 127) / 128;           // 7813 (4 waves x 32 edges)
    k_prep_w1<<<dim3((2 * 192 * HD + 255) / 256), b256, 0, stream>>>(emlp1_W, w1t);
    k_prep_w64<<<dim3((2 * HD * HD + 255) / 256), b256, 0, stream>>>(emlp2_W, w2t);
    k_prep_w64<<<dim3((2 * HD * HD + 255) / 256), b256, 0, stream>>>(elin_W, welt);
    k_prep_wpad<<<dim3((HD * 32 + 255) / 256), b256, 0, stream>>>(edge_W, wpad);
    k_node_proj<<<dim3((NN + 3) / 4), b256, 0, stream>>>(x, node_W, node_b, hbuf);

    // ---- layer 0: fused edge_proj + gine_msg(0) ----
    hipMemsetAsync(agg, 0, (size_t)NN * HD * sizeof(float), stream);
    hipMemsetAsync(bnst, 0, 128 * sizeof(float), stream);
    k_edge_proj_gine<<<dim3(WG2), b256, 0, stream>>>(
        eattr, hbuf, src, dst, wpad, edge_b, welt, elin_b, eab, agg);
    k_node_mlp<<<dim3((NN + 255) / 256), b256, 0, stream>>>(
        hbuf, agg, mlp1_W, mlp1_b, mlp2_W, mlp2_b, out2);
    k_bnstats<<<dim3(256), b256, 0, stream>>>(out2, bnst);
    k_bn_h<<<dim3((NN * HD + 255) / 256), b256, 0, stream>>>(
        out2, bnst, bn_gamma, bn_beta, hbuf, hbf, hout, 0);
    // edge_upd(0) + fused gine_msg(1)
    hipMemsetAsync(agg, 0, (size_t)NN * HD * sizeof(float), stream);
    hipMemsetAsync(bnst, 0, 128 * sizeof(float), stream);
    k_edge_upd_fused<<<dim3(WG2), b256, 0, stream>>>(
        hbf, eab, src, dst, w1t, emlp1_b, w2t, emlp2_b,
        hbuf, welt + (size_t)HD * HD, elin_b + HD, agg);

    // ---- layer 1 ----
    k_node_mlp<<<dim3((NN + 255) / 256), b256, 0, stream>>>(
        hbuf, agg, mlp1_W + HD * HD, mlp1_b + HD,
        mlp2_W + HD * HD, mlp2_b + HD, out2);
    k_bnstats<<<dim3(256), b256, 0, stream>>>(out2, bnst);
    k_bn_h<<<dim3((NN * HD + 255) / 256), b256, 0, stream>>>(
        out2, bnst, bn_gamma + HD, bn_beta + HD, hbuf, hbf, hout, 1);
    k_edge_upd_final<<<dim3(WG2), b256, 0, stream>>>(
        hbf, eab, eaout, src, dst,
        w1t + (size_t)192 * HD, emlp1_b + HD,
        w2t + (size_t)HD * HD, emlp2_b + HD);
}

// Round 21
// 1013.381 us; speedup vs baseline: 1.0467x; 1.0467x over previous
//
#include <hip/hip_runtime.h>
#include <hip/hip_bf16.h>

#define NN 50000
#define NE 1000000
#define NF 32
#define ED 16
#define HD 64
#define BN_EPS 1e-5f

typedef unsigned short u16;
typedef __attribute__((ext_vector_type(8))) short bf16x8;
typedef __attribute__((ext_vector_type(4))) float f32x4;

// wave-level LDS fence: ds ops complete + no compiler reordering (rule #18)
#define WAVE_SYNC() do { \
    asm volatile("s_waitcnt lgkmcnt(0)" ::: "memory"); \
    __builtin_amdgcn_sched_barrier(0); \
} while (0)

__device__ __forceinline__ u16 f2b(float x)
{
    __hip_bfloat16 b = __float2bfloat16(x);
    u16 u; __builtin_memcpy(&u, &b, 2); return u;
}
__device__ __forceinline__ float b2f(u16 u)
{
    uint v = (uint)u << 16; float f; __builtin_memcpy(&f, &v, 4); return f;
}

// ---------------- diag: fill an f32 region with a sentinel constant
__global__ __launch_bounds__(256) void k_fill(float* p, float v, size_t n)
{
    size_t i = (size_t)blockIdx.x * 256 + threadIdx.x;
    if (i < n) p[i] = v;
}

// rank-4 update: o += t * W[0:4][:]  (weights wave-uniform)
__device__ __forceinline__ void gemm4(float (&o)[HD], float4 t, const float* __restrict__ Wr)
{
    #pragma unroll
    for (int f = 0; f < HD; f++) o[f] = fmaf(t.x, Wr[f], o[f]);
    #pragma unroll
    for (int f = 0; f < HD; f++) o[f] = fmaf(t.y, Wr[HD + f], o[f]);
    #pragma unroll
    for (int f = 0; f < HD; f++) o[f] = fmaf(t.z, Wr[2 * HD + f], o[f]);
    #pragma unroll
    for (int f = 0; f < HD; f++) o[f] = fmaf(t.w, Wr[3 * HD + f], o[f]);
}

// pack 8 consecutive f32 -> bf16x8 fragment (in registers)
__device__ __forceinline__ bf16x8 pack8(const float* __restrict__ p)
{
    float4 v0 = ((const float4*)p)[0];
    float4 v1 = ((const float4*)p)[1];
    union { uint u[4]; bf16x8 v; } r;
    r.u[0] = (uint)f2b(v0.x) | ((uint)f2b(v0.y) << 16);
    r.u[1] = (uint)f2b(v0.z) | ((uint)f2b(v0.w) << 16);
    r.u[2] = (uint)f2b(v1.x) | ((uint)f2b(v1.y) << 16);
    r.u[3] = (uint)f2b(v1.z) | ((uint)f2b(v1.w) << 16);
    return r.v;
}

// ---------------- prep: W1[l][k][f] (f32) -> w1t[l][f][k] (bf16), k=0..191
__global__ __launch_bounds__(256) void k_prep_w1(const float* __restrict__ W, u16* __restrict__ out)
{
    int idx = blockIdx.x * 256 + threadIdx.x;
    if (idx >= 2 * 192 * HD) return;
    int l = idx / (192 * HD), r = idx % (192 * HD), k = r / HD, f = r % HD;
    out[l * 192 * HD + f * 192 + k] = f2b(W[idx]);
}
// ---------------- prep: 2 layers of [64][64] (k,f) -> (f,k) bf16
__global__ __launch_bounds__(256) void k_prep_w64(const float* __restrict__ W, u16* __restrict__ out)
{
    int idx = blockIdx.x * 256 + threadIdx.x;
    if (idx >= 2 * HD * HD) return;
    int l = idx / (HD * HD), r = idx % (HD * HD), k = r / HD, f = r % HD;
    out[l * HD * HD + f * HD + k] = f2b(W[idx]);
}
// ---------------- prep: edge_W [16][64] (k,f) -> padded [64][32] (f,k), k>=16 -> 0
__global__ __launch_bounds__(256) void k_prep_wpad(const float* __restrict__ W, u16* __restrict__ out)
{
    int idx = blockIdx.x * 256 + threadIdx.x;
    if (idx >= HD * 32) return;
    int f = idx / 32, k = idx % 32;
    out[f * 32 + k] = (k < ED) ? f2b(W[k * HD + f]) : (u16)0;
}

// ---------------- K1: h = x @ node_W + node_b  (wave per node, K=32 via shfl)
__global__ __launch_bounds__(256) void k_node_proj(
    const float* __restrict__ x, const float* __restrict__ W,
    const float* __restrict__ b, float* __restrict__ h)
{
    __shared__ float sW[NF * HD];   // 8 KB
    for (int t = threadIdx.x; t < NF * HD; t += 256) sW[t] = W[t];
    __syncthreads();
    int lane = threadIdx.x & 63, wv = threadIdx.x >> 6;
    int n = blockIdx.x * 4 + wv;
    if (n >= NN) return;
    float a = (lane < NF) ? x[(size_t)n * NF + lane] : 0.f;
    float acc = b[lane];
    #pragma unroll
    for (int k = 0; k < NF; k++) acc = fmaf(__shfl(a, k), sW[k * HD + lane], acc);
    h[(size_t)n * HD + lane] = acc;
}

// ---------------- K2+K3 FUSED: eab = bf16(attr@edge_W+b); msg = relu(h[src]+eab@welt+belin)
// 32 edges/wave; proj via MFMA (K=16 zero-padded to 32); atomic agg[dst]
__global__ __launch_bounds__(256) void k_edge_proj_gine(
    const float* __restrict__ attr, const float* __restrict__ h,
    const int* __restrict__ src, const int* __restrict__ dst,
    const u16* __restrict__ wpadt, const float* __restrict__ eb,
    const u16* __restrict__ welt, const float* __restrict__ belin,
    u16* __restrict__ eab, float* __restrict__ agg)
{
    __shared__ u16 sO[4][32 * 72];   // 18 KB
    const int lane = threadIdx.x & 63, wv = threadIdx.x >> 6;
    const size_t base = ((size_t)blockIdx.x * 4 + wv) * 32;
    if (base >= NE) return;
    u16* sOw = sO[wv];
    const int c = lane & 15, g = lane >> 4;

    // ---- A-frags from attr: K=16 real (g<2), zero else ----
    bf16x8 zero8 = {0, 0, 0, 0, 0, 0, 0, 0};
    bf16x8 ap[2];
    #pragma unroll
    for (int s = 0; s < 2; s++)
        ap[s] = (g < 2) ? pack8(attr + (base + 16 * s + c) * ED + 8 * g) : zero8;

    // ---- proj MFMA: ea = attr @ edge_W + eb ----
    f32x4 acc[2][4];
    #pragma unroll
    for (int s = 0; s < 2; s++)
        #pragma unroll
        for (int tt = 0; tt < 4; tt++) {
            float bv = eb[tt * 16 + c];
            acc[s][tt] = (f32x4){bv, bv, bv, bv};
        }
    #pragma unroll
    for (int tt = 0; tt < 4; tt++) {
        bf16x8 bw = *(const bf16x8*)&wpadt[(tt * 16 + c) * 32 + 8 * g];
        acc[0][tt] = __builtin_amdgcn_mfma_f32_16x16x32_bf16(ap[0], bw, acc[0][tt], 0, 0, 0);
        acc[1][tt] = __builtin_amdgcn_mfma_f32_16x16x32_bf16(ap[1], bw, acc[1][tt], 0, 0, 0);
    }
    // ---- write eab (global D-layout + LDS transpose) ----
    #pragma unroll
    for (int s = 0; s < 2; s++)
        #pragma unroll
        for (int tt = 0; tt < 4; tt++)
            #pragma unroll
            for (int r = 0; r < 4; r++) {
                u16 nb = f2b(acc[s][tt][r]);
                eab[(base + 16 * s + 4 * g + r) * HD + tt * 16 + c] = nb;
                sOw[(16 * s + 4 * g + r) * 72 + tt * 16 + c] = nb;
            }
    WAVE_SYNC();

    // ---- fused gine_msg(0): msg = relu(h[src] + eab @ welt + belin) ----
    bf16x8 A3[2][2];
    #pragma unroll
    for (int s = 0; s < 2; s++) {
        A3[s][0] = *(const bf16x8*)&sOw[(16 * s + c) * 72 + 8 * g];
        A3[s][1] = *(const bf16x8*)&sOw[(16 * s + c) * 72 + 32 + 8 * g];
    }
    f32x4 acc3[2][4];
    #pragma unroll
    for (int s = 0; s < 2; s++)
        #pragma unroll
        for (int tt = 0; tt < 4; tt++) {
            float bv = belin[tt * 16 + c];
            acc3[s][tt] = (f32x4){bv, bv, bv, bv};
        }
    #pragma unroll
    for (int ki = 0; ki < 2; ki++)
        #pragma unroll
        for (int tt = 0; tt < 4; tt++) {
            bf16x8 bw = *(const bf16x8*)&welt[(tt * 16 + c) * HD + ki * 32 + 8 * g];
            acc3[0][tt] = __builtin_amdgcn_mfma_f32_16x16x32_bf16(A3[0][ki], bw, acc3[0][tt], 0, 0, 0);
            acc3[1][tt] = __builtin_amdgcn_mfma_f32_16x16x32_bf16(A3[1][ki], bw, acc3[1][tt], 0, 0, 0);
        }
    int sv2[2][4], dv2[2][4];
    #pragma unroll
    for (int s = 0; s < 2; s++)
        #pragma unroll
        for (int r = 0; r < 4; r++) {
            sv2[s][r] = src[base + 16 * s + 4 * g + r];
            dv2[s][r] = dst[base + 16 * s + 4 * g + r];
        }
    #pragma unroll
    for (int s = 0; s < 2; s++)
        #pragma unroll
        for (int tt = 0; tt < 4; tt++)
            #pragma unroll
            for (int r = 0; r < 4; r++) {
                float m = fmaxf(acc3[s][tt][r] + h[(size_t)sv2[s][r] * HD + tt * 16 + c], 0.f);
                unsafeAtomicAdd(&agg[(size_t)dv2[s][r] * HD + tt * 16 + c], m);
            }
}

// ---------------- K4: out2 = mlp2(relu(mlp1(h+agg)))  (thread per node)
__global__ __launch_bounds__(256) void k_node_mlp(
    const float* __restrict__ h, const float* __restrict__ agg,
    const float* __restrict__ W1, const float* __restrict__ b1,
    const float* __restrict__ W2, const float* __restrict__ b2,
    float* __restrict__ out2)
{
    int n = blockIdx.x * 256 + threadIdx.x;
    if (n >= NN) return;
    float o[HD];
    #pragma unroll
    for (int f = 0; f < HD; f++) o[f] = b1[f];
    const float4* hr = (const float4*)(h + (size_t)n * HD);
    const float4* ar = (const float4*)(agg + (size_t)n * HD);
    #pragma unroll 4
    for (int k4 = 0; k4 < 16; k4++) {
        float4 t1 = hr[k4], t2 = ar[k4];
        float4 t = make_float4(t1.x + t2.x, t1.y + t2.y, t1.z + t2.z, t1.w + t2.w);
        gemm4(o, t, W1 + (k4 * 4) * HD);
    }
    #pragma unroll
    for (int k = 0; k < HD; k++) o[k] = fmaxf(o[k], 0.f);
    #pragma unroll
    for (int c = 0; c < 4; c++) {
        float p[16];
        #pragma unroll
        for (int j = 0; j < 16; j++) p[j] = b2[c * 16 + j];
        for (int k = 0; k < HD; k++) {
            const float* Wr = W2 + k * HD + c * 16;
            #pragma unroll
            for (int j = 0; j < 16; j++) p[j] = fmaf(o[k], Wr[j], p[j]);
        }
        float4* orow = (float4*)(out2 + (size_t)n * HD + c * 16);
        #pragma unroll
        for (int q = 0; q < 4; q++)
            orow[q] = make_float4(p[4*q], p[4*q+1], p[4*q+2], p[4*q+3]);
    }
}

// ---------------- K4b: BN stats reduction (lane = feature, coalesced rows)
__global__ __launch_bounds__(256) void k_bnstats(
    const float* __restrict__ out2, float* __restrict__ bnst)
{
    int f = threadIdx.x & 63;
    int row0 = blockIdx.x * 4 + (threadIdx.x >> 6);
    float s = 0.f, q = 0.f;
    for (int r = row0; r < NN; r += gridDim.x * 4) {
        float v = out2[(size_t)r * HD + f];
        s += v; q += v * v;
    }
    unsafeAtomicAdd(&bnst[f], s);
    unsafeAtomicAdd(&bnst[HD + f], q);
}

// ---------------- K5: BN + h = (h + relu(out2*sc+sh)) * 0.5 ; also bf16 h copy
__global__ __launch_bounds__(256) void k_bn_h(
    const float* __restrict__ out2, const float* __restrict__ bnst,
    const float* __restrict__ gamma, const float* __restrict__ beta,
    float* __restrict__ h, u16* __restrict__ hbf, float* __restrict__ hout, int last)
{
    size_t idx = (size_t)blockIdx.x * 256 + threadIdx.x;
    if (idx >= (size_t)NN * HD) return;
    int f = (int)(idx & 63);
    float mu  = bnst[f] * (1.f / NN);
    float var = bnst[HD + f] * (1.f / NN) - mu * mu;
    float sc  = gamma[f] * rsqrtf(var + BN_EPS);
    float sh  = beta[f] - mu * sc;
    float o   = fmaxf(fmaf(out2[idx], sc, sh), 0.f);
    float hn  = (h[idx] + o) * 0.5f;
    h[idx] = hn;
    hbf[idx] = f2b(hn);
    if (last) hout[idx] = hn;
}

// shared core: layer-1 + layer-2 MFMA for the edge MLP (32 edges/wave)
// returns acc2 (update, D layout). A-fragments direct from global bf16.
__device__ __forceinline__ void edge_mlp_core(
    const u16* __restrict__ hbf, const u16* __restrict__ eab,
    const int* __restrict__ src, const int* __restrict__ dst,
    const u16* __restrict__ w1t, const float* __restrict__ b1,
    const u16* __restrict__ w2t, const float* __restrict__ b2,
    u16* sOw, size_t base, int c, int g, f32x4 (&acc2)[2][4])
{
    int sv[2], dv[2];
    #pragma unroll
    for (int s = 0; s < 2; s++) {
        sv[s] = src[base + 16 * s + c];
        dv[s] = dst[base + 16 * s + c];
    }
    bf16x8 A[3][2][2];
    #pragma unroll
    for (int s = 0; s < 2; s++) {
        const u16* hs = &hbf[(size_t)sv[s] * HD + 8 * g];
        A[0][s][0] = *(const bf16x8*)hs;
        A[0][s][1] = *(const bf16x8*)(hs + 32);
        const u16* hd = &hbf[(size_t)dv[s] * HD + 8 * g];
        A[1][s][0] = *(const bf16x8*)hd;
        A[1][s][1] = *(const bf16x8*)(hd + 32);
        const u16* ep = &eab[(base + 16 * s + c) * HD + 8 * g];
        A[2][s][0] = *(const bf16x8*)ep;
        A[2][s][1] = *(const bf16x8*)(ep + 32);
    }
    f32x4 acc[2][4];
    #pragma unroll
    for (int s = 0; s < 2; s++)
        #pragma unroll
        for (int tt = 0; tt < 4; tt++) {
            float bv = b1[tt * 16 + c];
            acc[s][tt] = (f32x4){bv, bv, bv, bv};
        }
    #pragma unroll
    for (int sec = 0; sec < 3; sec++)
        #pragma unroll
        for (int ki = 0; ki < 2; ki++)
            #pragma unroll
            for (int tt = 0; tt < 4; tt++) {
                bf16x8 bw = *(const bf16x8*)&w1t[(tt * 16 + c) * 192 + sec * 64 + ki * 32 + 8 * g];
                acc[0][tt] = __builtin_amdgcn_mfma_f32_16x16x32_bf16(A[sec][0][ki], bw, acc[0][tt], 0, 0, 0);
                acc[1][tt] = __builtin_amdgcn_mfma_f32_16x16x32_bf16(A[sec][1][ki], bw, acc[1][tt], 0, 0, 0);
            }
    #pragma unroll
    for (int s = 0; s < 2; s++)
        #pragma unroll
        for (int tt = 0; tt < 4; tt++)
            #pragma unroll
            for (int r = 0; r < 4; r++)
                sOw[(16 * s + 4 * g + r) * 72 + tt * 16 + c] = f2b(fmaxf(acc[s][tt][r], 0.f));
    WAVE_SYNC();
    bf16x8 A2[2][2];
    #pragma unroll
    for (int s = 0; s < 2; s++) {
        A2[s][0] = *(const bf16x8*)&sOw[(16 * s + c) * 72 + 8 * g];
        A2[s][1] = *(const bf16x8*)&sOw[(16 * s + c) * 72 + 32 + 8 * g];
    }
    WAVE_SYNC();
    #pragma unroll
    for (int s = 0; s < 2; s++)
        #pragma unroll
        for (int tt = 0; tt < 4; tt++) {
            float bv = b2[tt * 16 + c];
            acc2[s][tt] = (f32x4){bv, bv, bv, bv};
        }
    #pragma unroll
    for (int ki = 0; ki < 2; ki++)
        #pragma unroll
        for (int tt = 0; tt < 4; tt++) {
            bf16x8 bw = *(const bf16x8*)&w2t[(tt * 16 + c) * HD + ki * 32 + 8 * g];
            acc2[0][tt] = __builtin_amdgcn_mfma_f32_16x16x32_bf16(A2[0][ki], bw, acc2[0][tt], 0, 0, 0);
            acc2[1][tt] = __builtin_amdgcn_mfma_f32_16x16x32_bf16(A2[1][ki], bw, acc2[1][tt], 0, 0, 0);
        }
}

// ---------------- K6a: edge_upd layer0 FUSED with gine_msg layer1 (R18-best form)
__global__ __launch_bounds__(256) void k_edge_upd_fused(
    const u16* __restrict__ hbf, u16* __restrict__ eab,
    const int* __restrict__ src, const int* __restrict__ dst,
    const u16* __restrict__ w1t, const float* __restrict__ b1,
    const u16* __restrict__ w2t, const float* __restrict__ b2,
    const float* __restrict__ h, const u16* __restrict__ welt,
    const float* __restrict__ belin, float* __restrict__ agg)
{
    __shared__ u16 sO[4][32 * 72];   // 18 KB
    const int lane = threadIdx.x & 63, wv = threadIdx.x >> 6;
    const size_t base = ((size_t)blockIdx.x * 4 + wv) * 32;
    if (base >= NE) return;
    u16* sOw = sO[wv];
    const int c = lane & 15, g = lane >> 4;

    f32x4 acc2[2][4];
    edge_mlp_core(hbf, eab, src, dst, w1t, b1, w2t, b2, sOw, base, c, g, acc2);

    // ---- eab_new = bf16(eab + 0.5*upd): store global (D-layout) + LDS ----
    #pragma unroll
    for (int s = 0; s < 2; s++)
        #pragma unroll
        for (int tt = 0; tt < 4; tt++)
            #pragma unroll
            for (int r = 0; r < 4; r++) {
                size_t a = (base + 16 * s + 4 * g + r) * HD + tt * 16 + c;
                u16 nb = f2b(b2f(eab[a]) + 0.5f * acc2[s][tt][r]);
                eab[a] = nb;
                sOw[(16 * s + 4 * g + r) * 72 + tt * 16 + c] = nb;
            }
    WAVE_SYNC();

    // ---- fused gine_msg (layer 1): msg = relu(h[src] + eab_new @ welt + belin) ----
    bf16x8 A3[2][2];
    #pragma unroll
    for (int s = 0; s < 2; s++) {
        A3[s][0] = *(const bf16x8*)&sOw[(16 * s + c) * 72 + 8 * g];
        A3[s][1] = *(const bf16x8*)&sOw[(16 * s + c) * 72 + 32 + 8 * g];
    }
    f32x4 acc3[2][4];
    #pragma unroll
    for (int s = 0; s < 2; s++)
        #pragma unroll
        for (int tt = 0; tt < 4; tt++) {
            float bv = belin[tt * 16 + c];
            acc3[s][tt] = (f32x4){bv, bv, bv, bv};
        }
    #pragma unroll
    for (int ki = 0; ki < 2; ki++)
        #pragma unroll
        for (int tt = 0; tt < 4; tt++) {
            bf16x8 bw = *(const bf16x8*)&welt[(tt * 16 + c) * HD + ki * 32 + 8 * g];
            acc3[0][tt] = __builtin_amdgcn_mfma_f32_16x16x32_bf16(A3[0][ki], bw, acc3[0][tt], 0, 0, 0);
            acc3[1][tt] = __builtin_amdgcn_mfma_f32_16x16x32_bf16(A3[1][ki], bw, acc3[1][tt], 0, 0, 0);
        }
    int sv2[2][4], dv2[2][4];
    #pragma unroll
    for (int s = 0; s < 2; s++)
        #pragma unroll
        for (int r = 0; r < 4; r++) {
            sv2[s][r] = src[base + 16 * s + 4 * g + r];
            dv2[s][r] = dst[base + 16 * s + 4 * g + r];
        }
    #pragma unroll
    for (int s = 0; s < 2; s++)
        #pragma unroll
        for (int tt = 0; tt < 4; tt++)
            #pragma unroll
            for (int r = 0; r < 4; r++) {
                float m = fmaxf(acc3[s][tt][r] + h[(size_t)sv2[s][r] * HD + tt * 16 + c], 0.f);
                unsafeAtomicAdd(&agg[(size_t)dv2[s][r] * HD + tt * 16 + c], m);
            }
}

// ---------------- K6b: edge_upd layer1 FINAL: f32 output to d_out (R18-best form)
__global__ __launch_bounds__(256) void k_edge_upd_final(
    const u16* __restrict__ hbf, const u16* __restrict__ eab,
    float* __restrict__ eaout,
    const int* __restrict__ src, const int* __restrict__ dst,
    const u16* __restrict__ w1t, const float* __restrict__ b1,
    const u16* __restrict__ w2t, const float* __restrict__ b2)
{
    __shared__ u16 sO[4][32 * 72];   // 18 KB
    const int lane = threadIdx.x & 63, wv = threadIdx.x >> 6;
    const size_t base = ((size_t)blockIdx.x * 4 + wv) * 32;
    if (base >= NE) return;
    u16* sOw = sO[wv];
    const int c = lane & 15, g = lane >> 4;

    f32x4 acc2[2][4];
    edge_mlp_core(hbf, eab, src, dst, w1t, b1, w2t, b2, sOw, base, c, g, acc2);

    #pragma unroll
    for (int s = 0; s < 2; s++)
        #pragma unroll
        for (int tt = 0; tt < 4; tt++)
            #pragma unroll
            for (int r = 0; r < 4; r++) {
                size_t a = (base + 16 * s + 4 * g + r) * HD + tt * 16 + c;
                eaout[a] = b2f(eab[a]) + 0.5f * acc2[s][tt][r];
            }
}

extern "C" void kernel_launch(void* const* d_in, const int* in_sizes, int n_in,
                              void* d_out, int out_size, void* d_ws, size_t ws_size,
                              hipStream_t stream)
{
    const float* x        = (const float*)d_in[0];
    const int*   ei       = (const int*)d_in[1];
    const float* eattr    = (const float*)d_in[2];
    const float* node_W   = (const float*)d_in[3];
    const float* node_b   = (const float*)d_in[4];
    const float* edge_W   = (const float*)d_in[5];
    const float* edge_b   = (const float*)d_in[6];
    const float* elin_W   = (const float*)d_in[7];
    const float* elin_b   = (const float*)d_in[8];
    const float* mlp1_W   = (const float*)d_in[9];
    const float* mlp1_b   = (const float*)d_in[10];
    const float* mlp2_W   = (const float*)d_in[11];
    const float* mlp2_b   = (const float*)d_in[12];
    const float* emlp1_W  = (const float*)d_in[13];
    const float* emlp1_b  = (const float*)d_in[14];
    const float* emlp2_W  = (const float*)d_in[15];
    const float* emlp2_b  = (const float*)d_in[16];
    const float* bn_gamma = (const float*)d_in[17];
    const float* bn_beta  = (const float*)d_in[18];

    // OUTPUT IS FLOAT32: h at [0, 3.2M), ea at [3.2M, 67.2M)
    float* hout = (float*)d_out;
    float* eaout = hout + (size_t)NN * HD;

    const int* src = ei;          // edge_index row-major (2, NE)
    const int* dst = ei + NE;

    float* hbuf = (float*)d_ws;
    float* agg  = hbuf + (size_t)NN * HD;
    float* out2 = agg + (size_t)NN * HD;
    float* bnst = out2 + (size_t)NN * HD;
    u16*   w1t  = (u16*)(bnst + 128);          // [2][64][192] bf16
    u16*   w2t  = w1t + 2 * 192 * HD;          // [2][64][64]  bf16
    u16*   welt = w2t + 2 * HD * HD;           // [2][64][64]  bf16 (elin)
    u16*   wpad = welt + 2 * HD * HD;          // [64][32]     bf16 (edge proj, padded)
    u16*   hbf  = wpad + HD * 32;              // [NN][64] bf16
    u16*   eab  = hbf + (size_t)NN * HD;       // [NE][64] bf16 (128 MB)
    size_t base_need = ((size_t)NN * HD * 3 + 128) * sizeof(float)
                     + (2 * 192 * HD + 4 * HD * HD + HD * 32 + (size_t)NN * HD
                        + (size_t)NE * HD) * sizeof(u16);

    // ---- host-side sanity sentinels (decodable through absmax) ----
    static const int exp_sizes[19] = {
        1600000, 2000000, 16000000, 2048, 64, 1024, 64,
        8192, 128, 8192, 128, 8192, 128, 24576, 128, 8192, 128, 128, 128};
    float sentinel = 0.f;
    if (n_in != 19) sentinel = 6000.f;
    else {
        for (int i = 0; i < 19; i++)
            if (in_sizes[i] != exp_sizes[i]) { sentinel = 2000.f + 32.f * i; break; }
    }
    if (sentinel == 0.f && ws_size < base_need) sentinel = 7000.f;
    if (sentinel != 0.f) {
        k_fill<<<dim3((unsigned)(((size_t)NN * HD + 255) / 256)), dim3(256), 0, stream>>>(
            hout, sentinel, (size_t)NN * HD);
        k_fill<<<dim3((unsigned)(((size_t)NE * HD + 255) / 256)), dim3(256), 0, stream>>>(
            eaout, 0.f, (size_t)NE * HD);
        return;
    }

    dim3 b256(256);
    const unsigned WG2 = (NE + 127) / 128;           // 7813 (4 waves x 32 edges)
    k_prep_w1<<<dim3((2 * 192 * HD + 255) / 256), b256, 0, stream>>>(emlp1_W, w1t);
    k_prep_w64<<<dim3((2 * HD * HD + 255) / 256), b256, 0, stream>>>(emlp2_W, w2t);
    k_prep_w64<<<dim3((2 * HD * HD + 255) / 256), b256, 0, stream>>>(elin_W, welt);
    k_prep_wpad<<<dim3((HD * 32 + 255) / 256), b256, 0, stream>>>(edge_W, wpad);
    k_node_proj<<<dim3((NN + 3) / 4), b256, 0, stream>>>(x, node_W, node_b, hbuf);

    // ---- layer 0: fused edge_proj + gine_msg(0) ----
    hipMemsetAsync(agg, 0, (size_t)NN * HD * sizeof(float), stream);
    hipMemsetAsync(bnst, 0, 128 * sizeof(float), stream);
    k_edge_proj_gine<<<dim3(WG2), b256, 0, stream>>>(
        eattr, hbuf, src, dst, wpad, edge_b, welt, elin_b, eab, agg);
    k_node_mlp<<<dim3((NN + 255) / 256), b256, 0, stream>>>(
        hbuf, agg, mlp1_W, mlp1_b, mlp2_W, mlp2_b, out2);
    k_bnstats<<<dim3(256), b256, 0, stream>>>(out2, bnst);
    k_bn_h<<<dim3((NN * HD + 255) / 256), b256, 0, stream>>>(
        out2, bnst, bn_gamma, bn_beta, hbuf, hbf, hout, 0);
    // edge_upd(0) + fused gine_msg(1)
    hipMemsetAsync(agg, 0, (size_t)NN * HD * sizeof(float), stream);
    hipMemsetAsync(bnst, 0, 128 * sizeof(float), stream);
    k_edge_upd_fused<<<dim3(WG2), b256, 0, stream>>>(
        hbf, eab, src, dst, w1t, emlp1_b, w2t, emlp2_b,
        hbuf, welt + (size_t)HD * HD, elin_b + HD, agg);

    // ---- layer 1 ----
    k_node_mlp<<<dim3((NN + 255) / 256), b256, 0, stream>>>(
        hbuf, agg, mlp1_W + HD * HD, mlp1_b + HD,
        mlp2_W + HD * HD, mlp2_b + HD, out2);
    k_bnstats<<<dim3(256), b256, 0, stream>>>(out2, bnst);
    k_bn_h<<<dim3((NN * HD + 255) / 256), b256, 0, stream>>>(
        out2, bnst, bn_gamma + HD, bn_beta + HD, hbuf, hbf, hout, 1);
    k_edge_upd_final<<<dim3(WG2), b256, 0, stream>>>(
        hbf, eab, eaout, src, dst,
        w1t + (size_t)192 * HD, emlp1_b + HD,
        w2t + (size_t)HD * HD, emlp2_b + HD);
}

// Round 22
// 987.116 us; speedup vs baseline: 1.0746x; 1.0266x over previous
//
#include <hip/hip_runtime.h>
#include <hip/hip_bf16.h>

#define NN 50000
#define NE 1000000
#define NF 32
#define ED 16
#define HD 64
#define BN_EPS 1e-5f

typedef unsigned short u16;
typedef __attribute__((ext_vector_type(8))) short bf16x8;
typedef __attribute__((ext_vector_type(4))) float f32x4;

// wave-level LDS fence: ds ops complete + no compiler reordering (rule #18)
#define WAVE_SYNC() do { \
    asm volatile("s_waitcnt lgkmcnt(0)" ::: "memory"); \
    __builtin_amdgcn_sched_barrier(0); \
} while (0)

__device__ __forceinline__ u16 f2b(float x)
{
    __hip_bfloat16 b = __float2bfloat16(x);
    u16 u; __builtin_memcpy(&u, &b, 2); return u;
}
__device__ __forceinline__ float b2f(u16 u)
{
    uint v = (uint)u << 16; float f; __builtin_memcpy(&f, &v, 4); return f;
}

// ---------------- diag: fill an f32 region with a sentinel constant
__global__ __launch_bounds__(256) void k_fill(float* p, float v, size_t n)
{
    size_t i = (size_t)blockIdx.x * 256 + threadIdx.x;
    if (i < n) p[i] = v;
}

// rank-4 update: o += t * W[0:4][:]  (weights wave-uniform)
__device__ __forceinline__ void gemm4(float (&o)[HD], float4 t, const float* __restrict__ Wr)
{
    #pragma unroll
    for (int f = 0; f < HD; f++) o[f] = fmaf(t.x, Wr[f], o[f]);
    #pragma unroll
    for (int f = 0; f < HD; f++) o[f] = fmaf(t.y, Wr[HD + f], o[f]);
    #pragma unroll
    for (int f = 0; f < HD; f++) o[f] = fmaf(t.z, Wr[2 * HD + f], o[f]);
    #pragma unroll
    for (int f = 0; f < HD; f++) o[f] = fmaf(t.w, Wr[3 * HD + f], o[f]);
}

// pack 8 consecutive f32 -> bf16x8 fragment (in registers)
__device__ __forceinline__ bf16x8 pack8(const float* __restrict__ p)
{
    float4 v0 = ((const float4*)p)[0];
    float4 v1 = ((const float4*)p)[1];
    union { uint u[4]; bf16x8 v; } r;
    r.u[0] = (uint)f2b(v0.x) | ((uint)f2b(v0.y) << 16);
    r.u[1] = (uint)f2b(v0.z) | ((uint)f2b(v0.w) << 16);
    r.u[2] = (uint)f2b(v1.x) | ((uint)f2b(v1.y) << 16);
    r.u[3] = (uint)f2b(v1.z) | ((uint)f2b(v1.w) << 16);
    return r.v;
}

// ---------------- consolidated prep: all weight transposes in one launch
// [0, 24576): w1t   W1[l][k][f]->out[l][f][k], k<192
// [24576, 32768): w2t  (k,f)->(f,k) 2 layers of 64x64
// [32768, 40960): welt (k,f)->(f,k) 2 layers of 64x64
// [40960, 43008): wpad edge_W [16][64]->(f,k) padded K=32
__global__ __launch_bounds__(256) void k_prep_all(
    const float* __restrict__ W1, const float* __restrict__ W2,
    const float* __restrict__ We, const float* __restrict__ Wp,
    u16* __restrict__ w1t, u16* __restrict__ w2t,
    u16* __restrict__ welt, u16* __restrict__ wpad)
{
    int idx = blockIdx.x * 256 + threadIdx.x;
    if (idx < 24576) {
        int l = idx / (192 * HD), r = idx % (192 * HD), k = r / HD, f = r % HD;
        w1t[l * 192 * HD + f * 192 + k] = f2b(W1[idx]);
    } else if (idx < 32768) {
        int i = idx - 24576;
        int l = i / (HD * HD), r = i % (HD * HD), k = r / HD, f = r % HD;
        w2t[l * HD * HD + f * HD + k] = f2b(W2[i]);
    } else if (idx < 40960) {
        int i = idx - 32768;
        int l = i / (HD * HD), r = i % (HD * HD), k = r / HD, f = r % HD;
        welt[l * HD * HD + f * HD + k] = f2b(We[i]);
    } else if (idx < 43008) {
        int i = idx - 40960;
        int f = i / 32, k = i % 32;
        wpad[f * 32 + k] = (k < ED) ? f2b(Wp[k * HD + f]) : (u16)0;
    }
}

// ---------------- K1: h = x @ node_W + node_b (+ zero agg for layer 0)
__global__ __launch_bounds__(256) void k_node_proj(
    const float* __restrict__ x, const float* __restrict__ W,
    const float* __restrict__ b, float* __restrict__ h, float* __restrict__ agg)
{
    __shared__ float sW[NF * HD];   // 8 KB
    for (int t = threadIdx.x; t < NF * HD; t += 256) sW[t] = W[t];
    __syncthreads();
    int lane = threadIdx.x & 63, wv = threadIdx.x >> 6;
    int n = blockIdx.x * 4 + wv;
    if (n >= NN) return;
    float a = (lane < NF) ? x[(size_t)n * NF + lane] : 0.f;
    float acc = b[lane];
    #pragma unroll
    for (int k = 0; k < NF; k++) acc = fmaf(__shfl(a, k), sW[k * HD + lane], acc);
    h[(size_t)n * HD + lane] = acc;
    agg[(size_t)n * HD + lane] = 0.f;          // replaces layer-0 memset
}

// ---------------- K2+K3 FUSED: eab = bf16(attr@edge_W+b); msg = relu(h[src]+eab@welt+belin)
// 32 edges/wave; proj via MFMA (K=16 zero-padded to 32); atomic agg[dst]
__global__ __launch_bounds__(256) void k_edge_proj_gine(
    const float* __restrict__ attr, const float* __restrict__ h,
    const int* __restrict__ src, const int* __restrict__ dst,
    const u16* __restrict__ wpadt, const float* __restrict__ eb,
    const u16* __restrict__ welt, const float* __restrict__ belin,
    u16* __restrict__ eab, float* __restrict__ agg, float* __restrict__ bnst)
{
    __shared__ u16 sO[4][32 * 72];   // 18 KB
    const int lane = threadIdx.x & 63, wv = threadIdx.x >> 6;
    if (blockIdx.x == 0 && threadIdx.x < 128) bnst[threadIdx.x] = 0.f;  // layer-0 bnst zero
    const size_t base = ((size_t)blockIdx.x * 4 + wv) * 32;
    if (base >= NE) return;
    u16* sOw = sO[wv];
    const int c = lane & 15, g = lane >> 4;

    // ---- A-frags from attr: K=16 real (g<2), zero else ----
    bf16x8 zero8 = {0, 0, 0, 0, 0, 0, 0, 0};
    bf16x8 ap[2];
    #pragma unroll
    for (int s = 0; s < 2; s++)
        ap[s] = (g < 2) ? pack8(attr + (base + 16 * s + c) * ED + 8 * g) : zero8;

    // ---- proj MFMA: ea = attr @ edge_W + eb ----
    f32x4 acc[2][4];
    #pragma unroll
    for (int s = 0; s < 2; s++)
        #pragma unroll
        for (int tt = 0; tt < 4; tt++) {
            float bv = eb[tt * 16 + c];
            acc[s][tt] = (f32x4){bv, bv, bv, bv};
        }
    #pragma unroll
    for (int tt = 0; tt < 4; tt++) {
        bf16x8 bw = *(const bf16x8*)&wpadt[(tt * 16 + c) * 32 + 8 * g];
        acc[0][tt] = __builtin_amdgcn_mfma_f32_16x16x32_bf16(ap[0], bw, acc[0][tt], 0, 0, 0);
        acc[1][tt] = __builtin_amdgcn_mfma_f32_16x16x32_bf16(ap[1], bw, acc[1][tt], 0, 0, 0);
    }
    // ---- write eab (global D-layout + LDS transpose) ----
    #pragma unroll
    for (int s = 0; s < 2; s++)
        #pragma unroll
        for (int tt = 0; tt < 4; tt++)
            #pragma unroll
            for (int r = 0; r < 4; r++) {
                u16 nb = f2b(acc[s][tt][r]);
                eab[(base + 16 * s + 4 * g + r) * HD + tt * 16 + c] = nb;
                sOw[(16 * s + 4 * g + r) * 72 + tt * 16 + c] = nb;
            }
    WAVE_SYNC();

    // ---- fused gine_msg(0): msg = relu(h[src] + eab @ welt + belin) ----
    bf16x8 A3[2][2];
    #pragma unroll
    for (int s = 0; s < 2; s++) {
        A3[s][0] = *(const bf16x8*)&sOw[(16 * s + c) * 72 + 8 * g];
        A3[s][1] = *(const bf16x8*)&sOw[(16 * s + c) * 72 + 32 + 8 * g];
    }
    f32x4 acc3[2][4];
    #pragma unroll
    for (int s = 0; s < 2; s++)
        #pragma unroll
        for (int tt = 0; tt < 4; tt++) {
            float bv = belin[tt * 16 + c];
            acc3[s][tt] = (f32x4){bv, bv, bv, bv};
        }
    #pragma unroll
    for (int ki = 0; ki < 2; ki++)
        #pragma unroll
        for (int tt = 0; tt < 4; tt++) {
            bf16x8 bw = *(const bf16x8*)&welt[(tt * 16 + c) * HD + ki * 32 + 8 * g];
            acc3[0][tt] = __builtin_amdgcn_mfma_f32_16x16x32_bf16(A3[0][ki], bw, acc3[0][tt], 0, 0, 0);
            acc3[1][tt] = __builtin_amdgcn_mfma_f32_16x16x32_bf16(A3[1][ki], bw, acc3[1][tt], 0, 0, 0);
        }
    int sv2[2][4], dv2[2][4];
    #pragma unroll
    for (int s = 0; s < 2; s++)
        #pragma unroll
        for (int r = 0; r < 4; r++) {
            sv2[s][r] = src[base + 16 * s + 4 * g + r];
            dv2[s][r] = dst[base + 16 * s + 4 * g + r];
        }
    #pragma unroll
    for (int s = 0; s < 2; s++)
        #pragma unroll
        for (int tt = 0; tt < 4; tt++)
            #pragma unroll
            for (int r = 0; r < 4; r++) {
                float m = fmaxf(acc3[s][tt][r] + h[(size_t)sv2[s][r] * HD + tt * 16 + c], 0.f);
                unsafeAtomicAdd(&agg[(size_t)dv2[s][r] * HD + tt * 16 + c], m);
            }
}

// ---------------- K4: out2 = mlp2(relu(mlp1(h+agg)))  (thread per node)
__global__ __launch_bounds__(256) void k_node_mlp(
    const float* __restrict__ h, const float* __restrict__ agg,
    const float* __restrict__ W1, const float* __restrict__ b1,
    const float* __restrict__ W2, const float* __restrict__ b2,
    float* __restrict__ out2)
{
    int n = blockIdx.x * 256 + threadIdx.x;
    if (n >= NN) return;
    float o[HD];
    #pragma unroll
    for (int f = 0; f < HD; f++) o[f] = b1[f];
    const float4* hr = (const float4*)(h + (size_t)n * HD);
    const float4* ar = (const float4*)(agg + (size_t)n * HD);
    #pragma unroll 4
    for (int k4 = 0; k4 < 16; k4++) {
        float4 t1 = hr[k4], t2 = ar[k4];
        float4 t = make_float4(t1.x + t2.x, t1.y + t2.y, t1.z + t2.z, t1.w + t2.w);
        gemm4(o, t, W1 + (k4 * 4) * HD);
    }
    #pragma unroll
    for (int k = 0; k < HD; k++) o[k] = fmaxf(o[k], 0.f);
    #pragma unroll
    for (int c = 0; c < 4; c++) {
        float p[16];
        #pragma unroll
        for (int j = 0; j < 16; j++) p[j] = b2[c * 16 + j];
        for (int k = 0; k < HD; k++) {
            const float* Wr = W2 + k * HD + c * 16;
            #pragma unroll
            for (int j = 0; j < 16; j++) p[j] = fmaf(o[k], Wr[j], p[j]);
        }
        float4* orow = (float4*)(out2 + (size_t)n * HD + c * 16);
        #pragma unroll
        for (int q = 0; q < 4; q++)
            orow[q] = make_float4(p[4*q], p[4*q+1], p[4*q+2], p[4*q+3]);
    }
}

// ---------------- K4b: BN stats reduction (lane = feature, coalesced rows)
__global__ __launch_bounds__(256) void k_bnstats(
    const float* __restrict__ out2, float* __restrict__ bnst)
{
    int f = threadIdx.x & 63;
    int row0 = blockIdx.x * 4 + (threadIdx.x >> 6);
    float s = 0.f, q = 0.f;
    for (int r = row0; r < NN; r += gridDim.x * 4) {
        float v = out2[(size_t)r * HD + f];
        s += v; q += v * v;
    }
    unsafeAtomicAdd(&bnst[f], s);
    unsafeAtomicAdd(&bnst[HD + f], q);
}

// ---------------- K5: BN + h = (h + relu(out2*sc+sh)) * 0.5 ; bf16 h copy;
//                  also zeroes agg for the next layer when !last
__global__ __launch_bounds__(256) void k_bn_h(
    const float* __restrict__ out2, const float* __restrict__ bnst,
    const float* __restrict__ gamma, const float* __restrict__ beta,
    float* __restrict__ h, u16* __restrict__ hbf, float* __restrict__ hout,
    float* __restrict__ agg, int last)
{
    size_t idx = (size_t)blockIdx.x * 256 + threadIdx.x;
    if (idx >= (size_t)NN * HD) return;
    int f = (int)(idx & 63);
    float mu  = bnst[f] * (1.f / NN);
    float var = bnst[HD + f] * (1.f / NN) - mu * mu;
    float sc  = gamma[f] * rsqrtf(var + BN_EPS);
    float sh  = beta[f] - mu * sc;
    float o   = fmaxf(fmaf(out2[idx], sc, sh), 0.f);
    float hn  = (h[idx] + o) * 0.5f;
    h[idx] = hn;
    hbf[idx] = f2b(hn);
    if (last) hout[idx] = hn;
    else      agg[idx] = 0.f;                  // replaces layer-1 memset
}

// shared core: layer-1 + layer-2 MFMA for the edge MLP (32 edges/wave)
// returns acc2 (update, D layout). A-fragments direct from global bf16.
__device__ __forceinline__ void edge_mlp_core(
    const u16* __restrict__ hbf, const u16* __restrict__ eab,
    const int* __restrict__ src, const int* __restrict__ dst,
    const u16* __restrict__ w1t, const float* __restrict__ b1,
    const u16* __restrict__ w2t, const float* __restrict__ b2,
    u16* sOw, size_t base, int c, int g, f32x4 (&acc2)[2][4])
{
    int sv[2], dv[2];
    #pragma unroll
    for (int s = 0; s < 2; s++) {
        sv[s] = src[base + 16 * s + c];
        dv[s] = dst[base + 16 * s + c];
    }
    bf16x8 A[3][2][2];
    #pragma unroll
    for (int s = 0; s < 2; s++) {
        const u16* hs = &hbf[(size_t)sv[s] * HD + 8 * g];
        A[0][s][0] = *(const bf16x8*)hs;
        A[0][s][1] = *(const bf16x8*)(hs + 32);
        const u16* hd = &hbf[(size_t)dv[s] * HD + 8 * g];
        A[1][s][0] = *(const bf16x8*)hd;
        A[1][s][1] = *(const bf16x8*)(hd + 32);
        const u16* ep = &eab[(base + 16 * s + c) * HD + 8 * g];
        A[2][s][0] = *(const bf16x8*)ep;
        A[2][s][1] = *(const bf16x8*)(ep + 32);
    }
    f32x4 acc[2][4];
    #pragma unroll
    for (int s = 0; s < 2; s++)
        #pragma unroll
        for (int tt = 0; tt < 4; tt++) {
            float bv = b1[tt * 16 + c];
            acc[s][tt] = (f32x4){bv, bv, bv, bv};
        }
    #pragma unroll
    for (int sec = 0; sec < 3; sec++)
        #pragma unroll
        for (int ki = 0; ki < 2; ki++)
            #pragma unroll
            for (int tt = 0; tt < 4; tt++) {
                bf16x8 bw = *(const bf16x8*)&w1t[(tt * 16 + c) * 192 + sec * 64 + ki * 32 + 8 * g];
                acc[0][tt] = __builtin_amdgcn_mfma_f32_16x16x32_bf16(A[sec][0][ki], bw, acc[0][tt], 0, 0, 0);
                acc[1][tt] = __builtin_amdgcn_mfma_f32_16x16x32_bf16(A[sec][1][ki], bw, acc[1][tt], 0, 0, 0);
            }
    #pragma unroll
    for (int s = 0; s < 2; s++)
        #pragma unroll
        for (int tt = 0; tt < 4; tt++)
            #pragma unroll
            for (int r = 0; r < 4; r++)
                sOw[(16 * s + 4 * g + r) * 72 + tt * 16 + c] = f2b(fmaxf(acc[s][tt][r], 0.f));
    WAVE_SYNC();
    bf16x8 A2[2][2];
    #pragma unroll
    for (int s = 0; s < 2; s++) {
        A2[s][0] = *(const bf16x8*)&sOw[(16 * s + c) * 72 + 8 * g];
        A2[s][1] = *(const bf16x8*)&sOw[(16 * s + c) * 72 + 32 + 8 * g];
    }
    WAVE_SYNC();
    #pragma unroll
    for (int s = 0; s < 2; s++)
        #pragma unroll
        for (int tt = 0; tt < 4; tt++) {
            float bv = b2[tt * 16 + c];
            acc2[s][tt] = (f32x4){bv, bv, bv, bv};
        }
    #pragma unroll
    for (int ki = 0; ki < 2; ki++)
        #pragma unroll
        for (int tt = 0; tt < 4; tt++) {
            bf16x8 bw = *(const bf16x8*)&w2t[(tt * 16 + c) * HD + ki * 32 + 8 * g];
            acc2[0][tt] = __builtin_amdgcn_mfma_f32_16x16x32_bf16(A2[0][ki], bw, acc2[0][tt], 0, 0, 0);
            acc2[1][tt] = __builtin_amdgcn_mfma_f32_16x16x32_bf16(A2[1][ki], bw, acc2[1][tt], 0, 0, 0);
        }
}

// ---------------- K6a: edge_upd layer0 FUSED with gine_msg layer1
__global__ __launch_bounds__(256) void k_edge_upd_fused(
    const u16* __restrict__ hbf, u16* __restrict__ eab,
    const int* __restrict__ src, const int* __restrict__ dst,
    const u16* __restrict__ w1t, const float* __restrict__ b1,
    const u16* __restrict__ w2t, const float* __restrict__ b2,
    const float* __restrict__ h, const u16* __restrict__ welt,
    const float* __restrict__ belin, float* __restrict__ agg,
    float* __restrict__ bnst)
{
    __shared__ u16 sO[4][32 * 72];   // 18 KB
    const int lane = threadIdx.x & 63, wv = threadIdx.x >> 6;
    if (blockIdx.x == 0 && threadIdx.x < 128) bnst[threadIdx.x] = 0.f;  // layer-1 bnst zero
    const size_t base = ((size_t)blockIdx.x * 4 + wv) * 32;
    if (base >= NE) return;
    u16* sOw = sO[wv];
    const int c = lane & 15, g = lane >> 4;

    f32x4 acc2[2][4];
    edge_mlp_core(hbf, eab, src, dst, w1t, b1, w2t, b2, sOw, base, c, g, acc2);

    // ---- eab_new = bf16(eab + 0.5*upd): store global (D-layout) + LDS ----
    #pragma unroll
    for (int s = 0; s < 2; s++)
        #pragma unroll
        for (int tt = 0; tt < 4; tt++)
            #pragma unroll
            for (int r = 0; r < 4; r++) {
                size_t a = (base + 16 * s + 4 * g + r) * HD + tt * 16 + c;
                u16 nb = f2b(b2f(eab[a]) + 0.5f * acc2[s][tt][r]);
                eab[a] = nb;
                sOw[(16 * s + 4 * g + r) * 72 + tt * 16 + c] = nb;
            }
    WAVE_SYNC();

    // ---- fused gine_msg (layer 1): msg = relu(h[src] + eab_new @ welt + belin) ----
    bf16x8 A3[2][2];
    #pragma unroll
    for (int s = 0; s < 2; s++) {
        A3[s][0] = *(const bf16x8*)&sOw[(16 * s + c) * 72 + 8 * g];
        A3[s][1] = *(const bf16x8*)&sOw[(16 * s + c) * 72 + 32 + 8 * g];
    }
    f32x4 acc3[2][4];
    #pragma unroll
    for (int s = 0; s < 2; s++)
        #pragma unroll
        for (int tt = 0; tt < 4; tt++) {
            float bv = belin[tt * 16 + c];
            acc3[s][tt] = (f32x4){bv, bv, bv, bv};
        }
    #pragma unroll
    for (int ki = 0; ki < 2; ki++)
        #pragma unroll
        for (int tt = 0; tt < 4; tt++) {
            bf16x8 bw = *(const bf16x8*)&welt[(tt * 16 + c) * HD + ki * 32 + 8 * g];
            acc3[0][tt] = __builtin_amdgcn_mfma_f32_16x16x32_bf16(A3[0][ki], bw, acc3[0][tt], 0, 0, 0);
            acc3[1][tt] = __builtin_amdgcn_mfma_f32_16x16x32_bf16(A3[1][ki], bw, acc3[1][tt], 0, 0, 0);
        }
    int sv2[2][4], dv2[2][4];
    #pragma unroll
    for (int s = 0; s < 2; s++)
        #pragma unroll
        for (int r = 0; r < 4; r++) {
            sv2[s][r] = src[base + 16 * s + 4 * g + r];
            dv2[s][r] = dst[base + 16 * s + 4 * g + r];
        }
    #pragma unroll
    for (int s = 0; s < 2; s++)
        #pragma unroll
        for (int tt = 0; tt < 4; tt++)
            #pragma unroll
            for (int r = 0; r < 4; r++) {
                float m = fmaxf(acc3[s][tt][r] + h[(size_t)sv2[s][r] * HD + tt * 16 + c], 0.f);
                unsafeAtomicAdd(&agg[(size_t)dv2[s][r] * HD + tt * 16 + c], m);
            }
}

// ---------------- K6b: edge_upd layer1 FINAL: f32 output to d_out
__global__ __launch_bounds__(256) void k_edge_upd_final(
    const u16* __restrict__ hbf, const u16* __restrict__ eab,
    float* __restrict__ eaout,
    const int* __restrict__ src, const int* __restrict__ dst,
    const u16* __restrict__ w1t, const float* __restrict__ b1,
    const u16* __restrict__ w2t, const float* __restrict__ b2)
{
    __shared__ u16 sO[4][32 * 72];   // 18 KB
    const int lane = threadIdx.x & 63, wv = threadIdx.x >> 6;
    const size_t base = ((size_t)blockIdx.x * 4 + wv) * 32;
    if (base >= NE) return;
    u16* sOw = sO[wv];
    const int c = lane & 15, g = lane >> 4;

    f32x4 acc2[2][4];
    edge_mlp_core(hbf, eab, src, dst, w1t, b1, w2t, b2, sOw, base, c, g, acc2);

    #pragma unroll
    for (int s = 0; s < 2; s++)
        #pragma unroll
        for (int tt = 0; tt < 4; tt++)
            #pragma unroll
            for (int r = 0; r < 4; r++) {
                size_t a = (base + 16 * s + 4 * g + r) * HD + tt * 16 + c;
                eaout[a] = b2f(eab[a]) + 0.5f * acc2[s][tt][r];
            }
}

extern "C" void kernel_launch(void* const* d_in, const int* in_sizes, int n_in,
                              void* d_out, int out_size, void* d_ws, size_t ws_size,
                              hipStream_t stream)
{
    const float* x        = (const float*)d_in[0];
    const int*   ei       = (const int*)d_in[1];
    const float* eattr    = (const float*)d_in[2];
    const float* node_W   = (const float*)d_in[3];
    const float* node_b   = (const float*)d_in[4];
    const float* edge_W   = (const float*)d_in[5];
    const float* edge_b   = (const float*)d_in[6];
    const float* elin_W   = (const float*)d_in[7];
    const float* elin_b   = (const float*)d_in[8];
    const float* mlp1_W   = (const float*)d_in[9];
    const float* mlp1_b   = (const float*)d_in[10];
    const float* mlp2_W   = (const float*)d_in[11];
    const float* mlp2_b   = (const float*)d_in[12];
    const float* emlp1_W  = (const float*)d_in[13];
    const float* emlp1_b  = (const float*)d_in[14];
    const float* emlp2_W  = (const float*)d_in[15];
    const float* emlp2_b  = (const float*)d_in[16];
    const float* bn_gamma = (const float*)d_in[17];
    const float* bn_beta  = (const float*)d_in[18];

    // OUTPUT IS FLOAT32: h at [0, 3.2M), ea at [3.2M, 67.2M)
    float* hout = (float*)d_out;
    float* eaout = hout + (size_t)NN * HD;

    const int* src = ei;          // edge_index row-major (2, NE)
    const int* dst = ei + NE;

    float* hbuf = (float*)d_ws;
    float* agg  = hbuf + (size_t)NN * HD;
    float* out2 = agg + (size_t)NN * HD;
    float* bnst = out2 + (size_t)NN * HD;
    u16*   w1t  = (u16*)(bnst + 128);          // [2][64][192] bf16
    u16*   w2t  = w1t + 2 * 192 * HD;          // [2][64][64]  bf16
    u16*   welt = w2t + 2 * HD * HD;           // [2][64][64]  bf16 (elin)
    u16*   wpad = welt + 2 * HD * HD;          // [64][32]     bf16 (edge proj, padded)
    u16*   hbf  = wpad + HD * 32;              // [NN][64] bf16
    u16*   eab  = hbf + (size_t)NN * HD;       // [NE][64] bf16 (128 MB)
    size_t base_need = ((size_t)NN * HD * 3 + 128) * sizeof(float)
                     + (2 * 192 * HD + 4 * HD * HD + HD * 32 + (size_t)NN * HD
                        + (size_t)NE * HD) * sizeof(u16);

    // ---- host-side sanity sentinels (decodable through absmax) ----
    static const int exp_sizes[19] = {
        1600000, 2000000, 16000000, 2048, 64, 1024, 64,
        8192, 128, 8192, 128, 8192, 128, 24576, 128, 8192, 128, 128, 128};
    float sentinel = 0.f;
    if (n_in != 19) sentinel = 6000.f;
    else {
        for (int i = 0; i < 19; i++)
            if (in_sizes[i] != exp_sizes[i]) { sentinel = 2000.f + 32.f * i; break; }
    }
    if (sentinel == 0.f && ws_size < base_need) sentinel = 7000.f;
    if (sentinel != 0.f) {
        k_fill<<<dim3((unsigned)(((size_t)NN * HD + 255) / 256)), dim3(256), 0, stream>>>(
            hout, sentinel, (size_t)NN * HD);
        k_fill<<<dim3((unsigned)(((size_t)NE * HD + 255) / 256)), dim3(256), 0, stream>>>(
            eaout, 0.f, (size_t)NE * HD);
        return;
    }

    dim3 b256(256);
    const unsigned WG2 = (NE + 127) / 128;           // 7813 (4 waves x 32 edges)
    k_prep_all<<<dim3((43008 + 255) / 256), b256, 0, stream>>>(
        emlp1_W, emlp2_W, elin_W, edge_W, w1t, w2t, welt, wpad);
    k_node_proj<<<dim3((NN + 3) / 4), b256, 0, stream>>>(x, node_W, node_b, hbuf, agg);

    // ---- layer 0: fused edge_proj + gine_msg(0) (zeroes bnst in block 0) ----
    k_edge_proj_gine<<<dim3(WG2), b256, 0, stream>>>(
        eattr, hbuf, src, dst, wpad, edge_b, welt, elin_b, eab, agg, bnst);
    k_node_mlp<<<dim3((NN + 255) / 256), b256, 0, stream>>>(
        hbuf, agg, mlp1_W, mlp1_b, mlp2_W, mlp2_b, out2);
    k_bnstats<<<dim3(256), b256, 0, stream>>>(out2, bnst);
    k_bn_h<<<dim3((NN * HD + 255) / 256), b256, 0, stream>>>(
        out2, bnst, bn_gamma, bn_beta, hbuf, hbf, hout, agg, 0);   // zeroes agg
    // edge_upd(0) + fused gine_msg(1) (zeroes bnst in block 0)
    k_edge_upd_fused<<<dim3(WG2), b256, 0, stream>>>(
        hbf, eab, src, dst, w1t, emlp1_b, w2t, emlp2_b,
        hbuf, welt + (size_t)HD * HD, elin_b + HD, agg, bnst);

    // ---- layer 1 ----
    k_node_mlp<<<dim3((NN + 255) / 256), b256, 0, stream>>>(
        hbuf, agg, mlp1_W + HD * HD, mlp1_b + HD,
        mlp2_W + HD * HD, mlp2_b + HD, out2);
    k_bnstats<<<dim3(256), b256, 0, stream>>>(out2, bnst);
    k_bn_h<<<dim3((NN * HD + 255) / 256), b256, 0, stream>>>(
        out2, bnst, bn_gamma + HD, bn_beta + HD, hbuf, hbf, hout, agg, 1);
    k_edge_upd_final<<<dim3(WG2), b256, 0, stream>>>(
        hbf, eab, eaout, src, dst,
        w1t + (size_t)192 * HD, emlp1_b + HD,
        w2t + (size_t)HD * HD, emlp2_b + HD);
}